// Round 1
// 2290.829 us; speedup vs baseline: 2.1793x; 2.1793x over previous
//
#include <hip/hip_runtime.h>

// Hierarchical RNN — MFMA dataflow, v12.
// v11 (768×1-wave blocks) was MALL-path bound: every wave privately re-read
// its 16KB own-B tile (+16KB ff-B) per step via agent-scope loads
// => ~20MB/step through the L2-bypass path (~2TB/s sustained) = 9.7us/step,
// with MfmaUtil/VALUBusy/HBM all <3%.
// v12 regroups each cohort (d, bt16) into 4 workgroups x 8 waves (512 thr):
// the cohort-shared 32KB B-operand is staged ONCE per wg into LDS
// (XOR-swizzled, conflict-free ds_read_b128 broadcast) => 8x MALL traffic cut
// and 8x poll cut (one polling wave per wg; siblings parked at s_barrier).
// Sync protocol = v11's proven scheme at wg granularity: store-only flags,
// ring-4 slab, WAR read-acks (own>=t-3, upper>=t-4), release via
// vmcnt-drain (__syncthreads) before flag store. Numerics identical to v11.

#define TSTEPS 512
#define BATCH  128
#define DMOD   3
#define NH     512
#define CCLS   2
#define OUT2   (DMOD * BATCH * NH)

typedef unsigned long long u64;
typedef unsigned int u32;
typedef __attribute__((ext_vector_type(8))) short bf16x8;
typedef __attribute__((ext_vector_type(4))) float f32x4;

__device__ __forceinline__ float bflo(u32 u) { return __uint_as_float(u << 16); }
__device__ __forceinline__ float bfhi(u32 u) { return __uint_as_float(u & 0xffff0000u); }
__device__ __forceinline__ unsigned short f2bf(float x) {
    u32 u = __float_as_uint(x);
    return (unsigned short)((u + 0x7fffu + ((u >> 16) & 1u)) >> 16);
}
__device__ __forceinline__ u64 pack4bf(float a, float b, float c, float d) {
    u32 lo = (u32)f2bf(a) | ((u32)f2bf(b) << 16);
    u32 hi = (u32)f2bf(c) | ((u32)f2bf(d) << 16);
    return (u64)lo | ((u64)hi << 32);
}
__device__ __forceinline__ float lrelu(float x) { return fmaxf(x, 0.01f * x); }

__device__ __forceinline__ u64 ld_h(const u64* p) {
    return __hip_atomic_load(p, __ATOMIC_RELAXED, __HIP_MEMORY_SCOPE_AGENT);
}
__device__ __forceinline__ void st_h(u64* p, u64 v) {
    __hip_atomic_store(p, v, __ATOMIC_RELAXED, __HIP_MEMORY_SCOPE_AGENT);
}
__device__ __forceinline__ int ld_slot(const int* p) {
    return __hip_atomic_load(p, __ATOMIC_RELAXED, __HIP_MEMORY_SCOPE_AGENT);
}
__device__ __forceinline__ void st_slot(int* p, int v) {
    __hip_atomic_store(p, v, __ATOMIC_RELAXED, __HIP_MEMORY_SCOPE_AGENT);
}

__global__ __launch_bounds__(512, 2)
void rnn_mfma(const float* __restrict__ data,
              const float* __restrict__ h0,
              const float* __restrict__ W_in,
              const float* __restrict__ b_in,
              const float* __restrict__ W_hh,
              const float* __restrict__ b_hh,
              const float* __restrict__ W_ff,
              const float* __restrict__ b_ff,
              const float* __restrict__ taus,
              const float* __restrict__ W_fc,
              const float* __restrict__ b_fc,
              float* __restrict__ out,
              int* __restrict__ wsI)
{
    const int wgid = blockIdx.x;        // 0..95
    const int d    = wgid >> 5;         // 0..2
    const int rr   = wgid & 31;
    const int bt   = rr >> 2;           // 0..7 (16-row b-tile)
    const int q    = rr & 3;            // 0..3 (8-wave nt quarter)
    const int w    = threadIdx.x >> 6;  // wave 0..7
    const int lane = threadIdx.x & 63;
    const int nt   = q * 8 + w;         // 0..31 (16-col n-tile)
    const int colb = lane & 15;         // C col = local b
    const int quad = lane >> 4;         // 0..3
    const int b    = bt * 16 + colb;
    const int n0   = nt * 16 + quad * 4;

    int* flags = wsI;                        // [96] wg write-progress
    int* rdfl  = wsI + 1024;                 // @4096 B: [96] wg read-progress
    u64* slab  = (u64*)((char*)wsI + 65536); // [4][3][128 b][128] u64 (bf16 h)

    __shared__ u64 lsO[2048];   // own-h tile [16 b][128 u64], XOR-swizzled
    __shared__ u64 lsF[2048];   // ff-h tile

    // ---- preload weights as A-fragments (A[m=lane&15][k=quad*8+j]) ----
    bf16x8 wOwn[16], wFf[16];
    {
        const int nrow = nt * 16 + colb;     // A m-index = n_out
        const float* gw = W_hh + ((size_t)d * NH + nrow) * NH;
        for (int kc = 0; kc < 16; ++kc) {
            int k0 = kc * 32 + quad * 8;
            union { unsigned short s[8]; bf16x8 v; } u;
            for (int j = 0; j < 8; ++j) {
                float x = gw[k0 + j];
                if (k0 + j == nrow) x = 0.f;   // zeroed diagonal
                u.s[j] = f2bf(x);
            }
            wOwn[kc] = u.v;
        }
        if (d > 0) {
            const float* gf = W_ff + ((size_t)(d - 1) * NH + nrow) * NH;
            for (int kc = 0; kc < 16; ++kc) {
                int k0 = kc * 32 + quad * 8;
                union { unsigned short s[8]; bf16x8 v; } u;
                for (int j = 0; j < 8; ++j) u.s[j] = f2bf(gf[k0 + j]);
                wFf[kc] = u.v;
            }
        }
    }

    // finalize constants for this lane's 4 n
    float wi4[4], cb4[4], al4[4], it4[4];
#pragma unroll
    for (int k = 0; k < 4; ++k) {
        int n = n0 + k;
        wi4[k] = W_in[d * NH + n];
        float cbv = b_hh[d * NH + n] + b_in[d * NH + n];
        if (d > 0) cbv += b_ff[(d - 1) * NH + n];
        cb4[k] = cbv;
        float tc = fmaxf(taus[d * NH + n], 1.0f);
        it4[k] = 1.0f / tc;
        al4[k] = 1.0f - it4[k];
    }

    const int cohBase = d * 32 + bt * 4;     // own cohort's 4 wg-flag base
    const int l3 = lane & 3;
    int* fmy = flags + cohBase + q;
    int* rmy = rdfl + cohBase + q;
    const int* fOwn = flags + cohBase + l3;
    const int* fLow = flags + (d > 0 ? cohBase - 32 : cohBase) + l3;
    const int* rOwn = rdfl + cohBase + l3;
    const int* rUp  = rdfl + (d < DMOD - 1 ? cohBase + 32 : cohBase) + l3;

    const int scol = threadIdx.x & 127;      // u64 col within 1KB row
    const int sr0  = threadIdx.x >> 7;       // row group 0..3
    const int cA   = scol ^ (sr0 << 1);            // swz for rows sr0, sr0+8
    const int cB   = scol ^ ((sr0 + 4) << 1);      // swz for rows sr0+4, sr0+12

    u64 prev = 0;

    for (int t = 0; t < TSTEPS; ++t) {
        // ---- dep spin (wave 0 only): own wg-flags >= t, lower >= t+1 ----
        if (w == 0 && (t > 0 || d > 0)) {
            while (1) {
                bool ok = true;
                if (lane < 4) { if (t > 0) ok = (ld_slot(fOwn) >= t); }
                else if (lane < 8) { if (d > 0) ok = (ld_slot(fLow) >= t + 1); }
                if (__all(ok)) break;
                __builtin_amdgcn_s_sleep(1);
            }
            asm volatile("" ::: "memory");
        }
        __syncthreads();   // deps ready; prev-step LDS reads long done

        // ---- cooperative stage: own h(t-1) + ff h_{d-1}(t) -> LDS ----
        if (t == 0) {
            const float* hp = h0 + ((size_t)(d * BATCH) + bt * 16) * NH;
            float4 x0 = *(const float4*)(hp + (size_t)(sr0     ) * NH + scol * 4);
            float4 x1 = *(const float4*)(hp + (size_t)(sr0 +  4) * NH + scol * 4);
            float4 x2 = *(const float4*)(hp + (size_t)(sr0 +  8) * NH + scol * 4);
            float4 x3 = *(const float4*)(hp + (size_t)(sr0 + 12) * NH + scol * 4);
            lsO[(sr0     ) * 128 + cA] = pack4bf(x0.x, x0.y, x0.z, x0.w);
            lsO[(sr0 +  4) * 128 + cB] = pack4bf(x1.x, x1.y, x1.z, x1.w);
            lsO[(sr0 +  8) * 128 + cA] = pack4bf(x2.x, x2.y, x2.z, x2.w);
            lsO[(sr0 + 12) * 128 + cB] = pack4bf(x3.x, x3.y, x3.z, x3.w);
        } else {
            const u64* sp = slab + (((size_t)((t - 1) & 3) * 3 + d) << 14)
                          + (size_t)(bt * 16) * 128 + scol;
            u64 v0 = ld_h(sp + (size_t)(sr0     ) * 128);
            u64 v1 = ld_h(sp + (size_t)(sr0 +  4) * 128);
            u64 v2 = ld_h(sp + (size_t)(sr0 +  8) * 128);
            u64 v3 = ld_h(sp + (size_t)(sr0 + 12) * 128);
            lsO[(sr0     ) * 128 + cA] = v0;
            lsO[(sr0 +  4) * 128 + cB] = v1;
            lsO[(sr0 +  8) * 128 + cA] = v2;
            lsO[(sr0 + 12) * 128 + cB] = v3;
        }
        if (d > 0) {
            const u64* gp = slab + (((size_t)(t & 3) * 3 + (d - 1)) << 14)
                          + (size_t)(bt * 16) * 128 + scol;
            u64 v0 = ld_h(gp + (size_t)(sr0     ) * 128);
            u64 v1 = ld_h(gp + (size_t)(sr0 +  4) * 128);
            u64 v2 = ld_h(gp + (size_t)(sr0 +  8) * 128);
            u64 v3 = ld_h(gp + (size_t)(sr0 + 12) * 128);
            lsF[(sr0     ) * 128 + cA] = v0;
            lsF[(sr0 +  4) * 128 + cB] = v1;
            lsF[(sr0 +  8) * 128 + cA] = v2;
            lsF[(sr0 + 12) * 128 + cB] = v3;
        }
        __syncthreads();   // LDS tiles complete (vmcnt+lgkm drained per wave)
        if (w == 0 && lane == 0) st_slot(rmy, t);   // wg slab-reads done

        // ---- MFMA from LDS: C[m=n_out][n=b], 16 own + 16 ff ----
        f32x4 acc = {0.f, 0.f, 0.f, 0.f};
        const int swz = (colb & 7) << 1;
        const int cq  = quad * 2;
        const u64* bO = lsO + (size_t)colb * 128;
#pragma unroll
        for (int kc = 0; kc < 16; ++kc) {
            bf16x8 bv = *(const bf16x8*)(bO + (((kc * 8 + cq) ^ swz)));
            acc = __builtin_amdgcn_mfma_f32_16x16x32_bf16(wOwn[kc], bv, acc, 0, 0, 0);
        }
        if (d > 0) {
            const u64* bF = lsF + (size_t)colb * 128;
#pragma unroll
            for (int kc = 0; kc < 16; ++kc) {
                bf16x8 bv = *(const bf16x8*)(bF + (((kc * 8 + cq) ^ swz)));
                acc = __builtin_amdgcn_mfma_f32_16x16x32_bf16(wFf[kc], bv, acc, 0, 0, 0);
            }
        }

        // ---- finalize (lane-local: 4 n for its b) ----
        float xs = data[t * BATCH + b];
        float h0f, h1f, h2f, h3f;
        if (t == 0) {
            float4 v = *(const float4*)(h0 + ((size_t)(d * BATCH) + b) * NH + n0);
            h0f = v.x; h1f = v.y; h2f = v.z; h3f = v.w;
        } else {
            h0f = bflo((u32)prev);         h1f = bfhi((u32)prev);
            h2f = bflo((u32)(prev >> 32)); h3f = bfhi((u32)(prev >> 32));
        }
        float p0 = acc.x + cb4[0] + xs * wi4[0];
        float p1 = acc.y + cb4[1] + xs * wi4[1];
        float p2 = acc.z + cb4[2] + xs * wi4[2];
        float p3 = acc.w + cb4[3] + xs * wi4[3];
        float n0v = al4[0] * h0f + lrelu(p0) * it4[0];
        float n1v = al4[1] * h1f + lrelu(p1) * it4[1];
        float n2v = al4[2] * h2f + lrelu(p2) * it4[2];
        float n3v = al4[3] * h3f + lrelu(p3) * it4[3];
        u64 pk = pack4bf(n0v, n1v, n2v, n3v);
        prev = pk;

        // ---- WAR guard (ring-4 slack; wave 0 polls, normally instant) ----
        if (w == 0 && t >= 4) {
            while (1) {
                bool ok = true;
                if (lane < 4) ok = (ld_slot(rOwn) >= t - 3);
                else if (lane < 8) { if (d < DMOD - 1) ok = (ld_slot(rUp) >= t - 4); }
                if (__all(ok)) break;
                __builtin_amdgcn_s_sleep(1);
            }
        }
        __syncthreads();   // WAR cleared before anyone stores

        st_h(slab + (((size_t)(t & 3) * 3 + d) << 14)
             + (size_t)b * 128 + (size_t)nt * 4 + quad, pk);
        if (t == TSTEPS - 1) {
            *(float4*)(out + ((size_t)(d * BATCH) + b) * NH + n0)
                = make_float4(n0v, n1v, n2v, n3v);
        }
        __syncthreads();   // vmcnt(0) drain per wave => payload acked
        if (w == 0 && lane == 0) st_slot(fmy, t + 1);
    }

    // ---- readout heads: wg q==0 wave 0; lane<32 -> (b=lane&15, c=lane>>4) ----
    if (q == 0 && w == 0) {
        while (1) {
            bool ok = true;
            if (lane < 4) ok = (ld_slot(fOwn) >= TSTEPS);
            if (__all(ok)) break;
            __builtin_amdgcn_s_sleep(2);
        }
        asm volatile("" ::: "memory");
        if (lane < 32) {
            const int bb = bt * 16 + (lane & 15);
            const int c  = (lane >> 4) & 1;
            const u64* hf = slab + (((size_t)3 * 3 + d) << 14) + (size_t)bb * 128;
            const float4* wf = (const float4*)(W_fc + ((size_t)(d * CCLS) + c) * NH);
            float s = b_fc[d * CCLS + c];
            for (int q2 = 0; q2 < 128; ++q2) {
                u64 u = ld_h(hf + q2);
                float4 ww = wf[q2];
                s += bflo((u32)u) * ww.x + bfhi((u32)u) * ww.y
                   + bflo((u32)(u >> 32)) * ww.z + bfhi((u32)(u >> 32)) * ww.w;
            }
            out[OUT2 + (size_t)(d * BATCH + bb) * CCLS + c] = s;
        }
    }
}

extern "C" void kernel_launch(void* const* d_in, const int* in_sizes, int n_in,
                              void* d_out, int out_size, void* d_ws, size_t ws_size,
                              hipStream_t stream) {
    const float* data = (const float*)d_in[0];
    const float* h0   = (const float*)d_in[1];
    const float* W_in = (const float*)d_in[2];
    const float* b_in = (const float*)d_in[3];
    const float* W_hh = (const float*)d_in[4];
    const float* b_hh = (const float*)d_in[5];
    const float* W_ff = (const float*)d_in[6];
    const float* b_ff = (const float*)d_in[7];
    const float* taus = (const float*)d_in[8];
    const float* W_fc = (const float*)d_in[9];
    const float* b_fc = (const float*)d_in[10];

    // no init: flag/rdfl poison 0xAAAAAAAA reads negative = "not done".
    hipLaunchKernelGGL(rnn_mfma, dim3(96), dim3(512), 0, stream,
                       data, h0, W_in, b_in, W_hh, b_hh, W_ff, b_ff,
                       taus, W_fc, b_fc, (float*)d_out, (int*)d_ws);
}

// Round 6
// 2288.593 us; speedup vs baseline: 2.1815x; 1.0010x over previous
//
#include <hip/hip_runtime.h>

// Hierarchical RNN — MFMA dataflow, v12-bisect (byte-identical re-run of the
// Round-1 kernel that passed at 2290.8us).
// Purpose: rounds 3-5 all failed with a Trio-nursery ExceptionGroup carrying
// ZERO timing markers. Theory A: broker/federation outage (kernel never ran).
// Theory B: v14's XCD-checkin hangs and the harness's hang path reports
// without timing. This proven kernel separates them: pass => infra up, v14
// is hang-guilty (drop placement-dependent fast path); fail => infra down.
// --- original v12 header ---
// v11 (768x1-wave blocks) was MALL-path bound: every wave privately re-read
// its 16KB own-B tile (+16KB ff-B) per step via agent-scope loads
// => ~20MB/step through the L2-bypass path (~2TB/s sustained) = 9.7us/step.
// v12 regroups each cohort (d, bt16) into 4 workgroups x 8 waves (512 thr):
// the cohort-shared 32KB B-operand is staged ONCE per wg into LDS
// (XOR-swizzled ds_read_b128 broadcast) => 8x MALL traffic cut and 8x poll
// cut (one polling wave per wg; siblings parked at s_barrier).
// Sync protocol = v11's proven scheme at wg granularity: store-only flags,
// ring-4 slab, WAR read-acks (own>=t-3, upper>=t-4), release via
// vmcnt-drain (__syncthreads) before flag store.

#define TSTEPS 512
#define BATCH  128
#define DMOD   3
#define NH     512
#define CCLS   2
#define OUT2   (DMOD * BATCH * NH)

typedef unsigned long long u64;
typedef unsigned int u32;
typedef __attribute__((ext_vector_type(8))) short bf16x8;
typedef __attribute__((ext_vector_type(4))) float f32x4;

__device__ __forceinline__ float bflo(u32 u) { return __uint_as_float(u << 16); }
__device__ __forceinline__ float bfhi(u32 u) { return __uint_as_float(u & 0xffff0000u); }
__device__ __forceinline__ unsigned short f2bf(float x) {
    u32 u = __float_as_uint(x);
    return (unsigned short)((u + 0x7fffu + ((u >> 16) & 1u)) >> 16);
}
__device__ __forceinline__ u64 pack4bf(float a, float b, float c, float d) {
    u32 lo = (u32)f2bf(a) | ((u32)f2bf(b) << 16);
    u32 hi = (u32)f2bf(c) | ((u32)f2bf(d) << 16);
    return (u64)lo | ((u64)hi << 32);
}
__device__ __forceinline__ float lrelu(float x) { return fmaxf(x, 0.01f * x); }

__device__ __forceinline__ u64 ld_h(const u64* p) {
    return __hip_atomic_load(p, __ATOMIC_RELAXED, __HIP_MEMORY_SCOPE_AGENT);
}
__device__ __forceinline__ void st_h(u64* p, u64 v) {
    __hip_atomic_store(p, v, __ATOMIC_RELAXED, __HIP_MEMORY_SCOPE_AGENT);
}
__device__ __forceinline__ int ld_slot(const int* p) {
    return __hip_atomic_load(p, __ATOMIC_RELAXED, __HIP_MEMORY_SCOPE_AGENT);
}
__device__ __forceinline__ void st_slot(int* p, int v) {
    __hip_atomic_store(p, v, __ATOMIC_RELAXED, __HIP_MEMORY_SCOPE_AGENT);
}

__global__ __launch_bounds__(512, 2)
void rnn_mfma(const float* __restrict__ data,
              const float* __restrict__ h0,
              const float* __restrict__ W_in,
              const float* __restrict__ b_in,
              const float* __restrict__ W_hh,
              const float* __restrict__ b_hh,
              const float* __restrict__ W_ff,
              const float* __restrict__ b_ff,
              const float* __restrict__ taus,
              const float* __restrict__ W_fc,
              const float* __restrict__ b_fc,
              float* __restrict__ out,
              int* __restrict__ wsI)
{
    const int wgid = blockIdx.x;        // 0..95
    const int d    = wgid >> 5;         // 0..2
    const int rr   = wgid & 31;
    const int bt   = rr >> 2;           // 0..7 (16-row b-tile)
    const int q    = rr & 3;            // 0..3 (8-wave nt quarter)
    const int w    = threadIdx.x >> 6;  // wave 0..7
    const int lane = threadIdx.x & 63;
    const int nt   = q * 8 + w;         // 0..31 (16-col n-tile)
    const int colb = lane & 15;         // C col = local b
    const int quad = lane >> 4;         // 0..3
    const int b    = bt * 16 + colb;
    const int n0   = nt * 16 + quad * 4;

    int* flags = wsI;                        // [96] wg write-progress
    int* rdfl  = wsI + 1024;                 // @4096 B: [96] wg read-progress
    u64* slab  = (u64*)((char*)wsI + 65536); // [4][3][128 b][128] u64 (bf16 h)

    __shared__ u64 lsO[2048];   // own-h tile [16 b][128 u64], XOR-swizzled
    __shared__ u64 lsF[2048];   // ff-h tile

    // ---- preload weights as A-fragments (A[m=lane&15][k=quad*8+j]) ----
    bf16x8 wOwn[16], wFf[16];
    {
        const int nrow = nt * 16 + colb;     // A m-index = n_out
        const float* gw = W_hh + ((size_t)d * NH + nrow) * NH;
        for (int kc = 0; kc < 16; ++kc) {
            int k0 = kc * 32 + quad * 8;
            union { unsigned short s[8]; bf16x8 v; } u;
            for (int j = 0; j < 8; ++j) {
                float x = gw[k0 + j];
                if (k0 + j == nrow) x = 0.f;   // zeroed diagonal
                u.s[j] = f2bf(x);
            }
            wOwn[kc] = u.v;
        }
        if (d > 0) {
            const float* gf = W_ff + ((size_t)(d - 1) * NH + nrow) * NH;
            for (int kc = 0; kc < 16; ++kc) {
                int k0 = kc * 32 + quad * 8;
                union { unsigned short s[8]; bf16x8 v; } u;
                for (int j = 0; j < 8; ++j) u.s[j] = f2bf(gf[k0 + j]);
                wFf[kc] = u.v;
            }
        }
    }

    // finalize constants for this lane's 4 n
    float wi4[4], cb4[4], al4[4], it4[4];
#pragma unroll
    for (int k = 0; k < 4; ++k) {
        int n = n0 + k;
        wi4[k] = W_in[d * NH + n];
        float cbv = b_hh[d * NH + n] + b_in[d * NH + n];
        if (d > 0) cbv += b_ff[(d - 1) * NH + n];
        cb4[k] = cbv;
        float tc = fmaxf(taus[d * NH + n], 1.0f);
        it4[k] = 1.0f / tc;
        al4[k] = 1.0f - it4[k];
    }

    const int cohBase = d * 32 + bt * 4;     // own cohort's 4 wg-flag base
    const int l3 = lane & 3;
    int* fmy = flags + cohBase + q;
    int* rmy = rdfl + cohBase + q;
    const int* fOwn = flags + cohBase + l3;
    const int* fLow = flags + (d > 0 ? cohBase - 32 : cohBase) + l3;
    const int* rOwn = rdfl + cohBase + l3;
    const int* rUp  = rdfl + (d < DMOD - 1 ? cohBase + 32 : cohBase) + l3;

    const int scol = threadIdx.x & 127;      // u64 col within 1KB row
    const int sr0  = threadIdx.x >> 7;       // row group 0..3
    const int cA   = scol ^ (sr0 << 1);            // swz for rows sr0, sr0+8
    const int cB   = scol ^ ((sr0 + 4) << 1);      // swz for rows sr0+4, sr0+12

    u64 prev = 0;

    for (int t = 0; t < TSTEPS; ++t) {
        // ---- dep spin (wave 0 only): own wg-flags >= t, lower >= t+1 ----
        if (w == 0 && (t > 0 || d > 0)) {
            while (1) {
                bool ok = true;
                if (lane < 4) { if (t > 0) ok = (ld_slot(fOwn) >= t); }
                else if (lane < 8) { if (d > 0) ok = (ld_slot(fLow) >= t + 1); }
                if (__all(ok)) break;
                __builtin_amdgcn_s_sleep(1);
            }
            asm volatile("" ::: "memory");
        }
        __syncthreads();   // deps ready; prev-step LDS reads long done

        // ---- cooperative stage: own h(t-1) + ff h_{d-1}(t) -> LDS ----
        if (t == 0) {
            const float* hp = h0 + ((size_t)(d * BATCH) + bt * 16) * NH;
            float4 x0 = *(const float4*)(hp + (size_t)(sr0     ) * NH + scol * 4);
            float4 x1 = *(const float4*)(hp + (size_t)(sr0 +  4) * NH + scol * 4);
            float4 x2 = *(const float4*)(hp + (size_t)(sr0 +  8) * NH + scol * 4);
            float4 x3 = *(const float4*)(hp + (size_t)(sr0 + 12) * NH + scol * 4);
            lsO[(sr0     ) * 128 + cA] = pack4bf(x0.x, x0.y, x0.z, x0.w);
            lsO[(sr0 +  4) * 128 + cB] = pack4bf(x1.x, x1.y, x1.z, x1.w);
            lsO[(sr0 +  8) * 128 + cA] = pack4bf(x2.x, x2.y, x2.z, x2.w);
            lsO[(sr0 + 12) * 128 + cB] = pack4bf(x3.x, x3.y, x3.z, x3.w);
        } else {
            const u64* sp = slab + (((size_t)((t - 1) & 3) * 3 + d) << 14)
                          + (size_t)(bt * 16) * 128 + scol;
            u64 v0 = ld_h(sp + (size_t)(sr0     ) * 128);
            u64 v1 = ld_h(sp + (size_t)(sr0 +  4) * 128);
            u64 v2 = ld_h(sp + (size_t)(sr0 +  8) * 128);
            u64 v3 = ld_h(sp + (size_t)(sr0 + 12) * 128);
            lsO[(sr0     ) * 128 + cA] = v0;
            lsO[(sr0 +  4) * 128 + cB] = v1;
            lsO[(sr0 +  8) * 128 + cA] = v2;
            lsO[(sr0 + 12) * 128 + cB] = v3;
        }
        if (d > 0) {
            const u64* gp = slab + (((size_t)(t & 3) * 3 + (d - 1)) << 14)
                          + (size_t)(bt * 16) * 128 + scol;
            u64 v0 = ld_h(gp + (size_t)(sr0     ) * 128);
            u64 v1 = ld_h(gp + (size_t)(sr0 +  4) * 128);
            u64 v2 = ld_h(gp + (size_t)(sr0 +  8) * 128);
            u64 v3 = ld_h(gp + (size_t)(sr0 + 12) * 128);
            lsF[(sr0     ) * 128 + cA] = v0;
            lsF[(sr0 +  4) * 128 + cB] = v1;
            lsF[(sr0 +  8) * 128 + cA] = v2;
            lsF[(sr0 + 12) * 128 + cB] = v3;
        }
        __syncthreads();   // LDS tiles complete (vmcnt+lgkm drained per wave)
        if (w == 0 && lane == 0) st_slot(rmy, t);   // wg slab-reads done

        // ---- MFMA from LDS: C[m=n_out][n=b], 16 own + 16 ff ----
        f32x4 acc = {0.f, 0.f, 0.f, 0.f};
        const int swz = (colb & 7) << 1;
        const int cq  = quad * 2;
        const u64* bO = lsO + (size_t)colb * 128;
#pragma unroll
        for (int kc = 0; kc < 16; ++kc) {
            bf16x8 bv = *(const bf16x8*)(bO + (((kc * 8 + cq) ^ swz)));
            acc = __builtin_amdgcn_mfma_f32_16x16x32_bf16(wOwn[kc], bv, acc, 0, 0, 0);
        }
        if (d > 0) {
            const u64* bF = lsF + (size_t)colb * 128;
#pragma unroll
            for (int kc = 0; kc < 16; ++kc) {
                bf16x8 bv = *(const bf16x8*)(bF + (((kc * 8 + cq) ^ swz)));
                acc = __builtin_amdgcn_mfma_f32_16x16x32_bf16(wFf[kc], bv, acc, 0, 0, 0);
            }
        }

        // ---- finalize (lane-local: 4 n for its b) ----
        float xs = data[t * BATCH + b];
        float h0f, h1f, h2f, h3f;
        if (t == 0) {
            float4 v = *(const float4*)(h0 + ((size_t)(d * BATCH) + b) * NH + n0);
            h0f = v.x; h1f = v.y; h2f = v.z; h3f = v.w;
        } else {
            h0f = bflo((u32)prev);         h1f = bfhi((u32)prev);
            h2f = bflo((u32)(prev >> 32)); h3f = bfhi((u32)(prev >> 32));
        }
        float p0 = acc.x + cb4[0] + xs * wi4[0];
        float p1 = acc.y + cb4[1] + xs * wi4[1];
        float p2 = acc.z + cb4[2] + xs * wi4[2];
        float p3 = acc.w + cb4[3] + xs * wi4[3];
        float n0v = al4[0] * h0f + lrelu(p0) * it4[0];
        float n1v = al4[1] * h1f + lrelu(p1) * it4[1];
        float n2v = al4[2] * h2f + lrelu(p2) * it4[2];
        float n3v = al4[3] * h3f + lrelu(p3) * it4[3];
        u64 pk = pack4bf(n0v, n1v, n2v, n3v);
        prev = pk;

        // ---- WAR guard (ring-4 slack; wave 0 polls, normally instant) ----
        if (w == 0 && t >= 4) {
            while (1) {
                bool ok = true;
                if (lane < 4) ok = (ld_slot(rOwn) >= t - 3);
                else if (lane < 8) { if (d < DMOD - 1) ok = (ld_slot(rUp) >= t - 4); }
                if (__all(ok)) break;
                __builtin_amdgcn_s_sleep(1);
            }
        }
        __syncthreads();   // WAR cleared before anyone stores

        st_h(slab + (((size_t)(t & 3) * 3 + d) << 14)
             + (size_t)b * 128 + (size_t)nt * 4 + quad, pk);
        if (t == TSTEPS - 1) {
            *(float4*)(out + ((size_t)(d * BATCH) + b) * NH + n0)
                = make_float4(n0v, n1v, n2v, n3v);
        }
        __syncthreads();   // vmcnt(0) drain per wave => payload acked
        if (w == 0 && lane == 0) st_slot(fmy, t + 1);
    }

    // ---- readout heads: wg q==0 wave 0; lane<32 -> (b=lane&15, c=lane>>4) ----
    if (q == 0 && w == 0) {
        while (1) {
            bool ok = true;
            if (lane < 4) ok = (ld_slot(fOwn) >= TSTEPS);
            if (__all(ok)) break;
            __builtin_amdgcn_s_sleep(2);
        }
        asm volatile("" ::: "memory");
        if (lane < 32) {
            const int bb = bt * 16 + (lane & 15);
            const int c  = (lane >> 4) & 1;
            const u64* hf = slab + (((size_t)3 * 3 + d) << 14) + (size_t)bb * 128;
            const float4* wf = (const float4*)(W_fc + ((size_t)(d * CCLS) + c) * NH);
            float s = b_fc[d * CCLS + c];
            for (int q2 = 0; q2 < 128; ++q2) {
                u64 u = ld_h(hf + q2);
                float4 ww = wf[q2];
                s += bflo((u32)u) * ww.x + bfhi((u32)u) * ww.y
                   + bflo((u32)(u >> 32)) * ww.z + bfhi((u32)(u >> 32)) * ww.w;
            }
            out[OUT2 + (size_t)(d * BATCH + bb) * CCLS + c] = s;
        }
    }
}

extern "C" void kernel_launch(void* const* d_in, const int* in_sizes, int n_in,
                              void* d_out, int out_size, void* d_ws, size_t ws_size,
                              hipStream_t stream) {
    const float* data = (const float*)d_in[0];
    const float* h0   = (const float*)d_in[1];
    const float* W_in = (const float*)d_in[2];
    const float* b_in = (const float*)d_in[3];
    const float* W_hh = (const float*)d_in[4];
    const float* b_hh = (const float*)d_in[5];
    const float* W_ff = (const float*)d_in[6];
    const float* b_ff = (const float*)d_in[7];
    const float* taus = (const float*)d_in[8];
    const float* W_fc = (const float*)d_in[9];
    const float* b_fc = (const float*)d_in[10];

    // no init: flag/rdfl poison 0xAAAAAAAA reads negative = "not done".
    hipLaunchKernelGGL(rnn_mfma, dim3(96), dim3(512), 0, stream,
                       data, h0, W_in, b_in, W_hh, b_hh, W_ff, b_ff,
                       taus, W_fc, b_fc, (float*)d_out, (int*)d_ws);
}